// Round 15
// baseline (288.438 us; speedup 1.0000x reference)
//
#include <hip/hip_runtime.h>
#include <hip/hip_bf16.h>
#include <math.h>

#define NB 2
#define NN 512
#define CS 256
#define CP 128
#define FD 64
#define NBINS 22
#define EPB 64

typedef __attribute__((ext_vector_type(8))) short bf16x8;
typedef __attribute__((ext_vector_type(4))) short bf16x4;
typedef __attribute__((ext_vector_type(4))) float f32x4;

__device__ __forceinline__ unsigned short f2bf_rne(float x) {
    unsigned int u = __float_as_uint(x);
    unsigned int r = (u + 0x7fffu + ((u >> 16) & 1u)) >> 16;
    return (unsigned short)r;
}
__device__ __forceinline__ float bf2f(unsigned short b) {
    return __uint_as_float(((unsigned int)b) << 16);
}
__device__ __forceinline__ unsigned short f2bf(float x) {
    __hip_bfloat16 h = __float2bfloat16(x);
    unsigned short u;
    __builtin_memcpy(&u, &h, 2);
    return u;
}

// Guarded-floor bin: exact fp32 boundary semantics of the reference scan.
__device__ __forceinline__ int bin_of(float d, float step) {
    const float fk = __fdiv_rn(__fsub_rn(d, 0.001f), step);
    int k0 = (int)fk;
    k0 = k0 < 1 ? 1 : (k0 > 20 ? 20 : k0);
    int row = -1;
    #pragma unroll
    for (int dk = -1; dk <= 1; ++dk) {
        const int k = k0 + dk;
        const float lo = __fadd_rn(0.001f, __fmul_rn((float)k, step));
        const float hi = (k == NBINS - 1)
                       ? 1e8f
                       : __fadd_rn(0.001f, __fmul_rn((float)(k + 1), step));
        row = (d > lo && d < hi) ? k : row;
    }
    return row;
}

__device__ __forceinline__ void calc_bins(const float* __restrict__ tt,
                                          const float* __restrict__ ts,
                                          int nodeI, int nj, float step,
                                          int& kT, int& kS) {
    float dx = __fsub_rn(tt[nodeI * 3 + 0], tt[nj * 3 + 0]);
    float dy = __fsub_rn(tt[nodeI * 3 + 1], tt[nj * 3 + 1]);
    float dz = __fsub_rn(tt[nodeI * 3 + 2], tt[nj * 3 + 2]);
    const float dT = sqrtf(__fadd_rn(__fadd_rn(__fmul_rn(dx, dx), __fmul_rn(dy, dy)), __fmul_rn(dz, dz)));
    dx = __fsub_rn(ts[nodeI * 3 + 0], ts[nj * 3 + 0]);
    dy = __fsub_rn(ts[nodeI * 3 + 1], ts[nj * 3 + 1]);
    dz = __fsub_rn(ts[nodeI * 3 + 2], ts[nj * 3 + 2]);
    const float dS = sqrtf(__fadd_rn(__fadd_rn(__fmul_rn(dx, dx), __fmul_rn(dy, dy)), __fmul_rn(dz, dz)));
    kT = bin_of(dT, step);
    kS = bin_of(dS, step);
}

// P1: h1 = relu(q_i + r_j + W1[binT] + W1[binS]) -> buf (bf16, swizzled)
__device__ __forceinline__ void build_h1(char* __restrict__ buf,
                                         const float* __restrict__ qr,
                                         const float* __restrict__ W1,
                                         int nodeI, int nj, int kT, int kS,
                                         int e1, int c0) {
    const float fT = (kT < 0) ? 0.0f : 1.0f;
    const float fS = (kS < 0) ? 0.0f : 1.0f;
    const float* qrow = qr + (size_t)nodeI * CP + c0;
    const float* rrow = qr + (size_t)(1024 + nj) * CP + c0;
    const float* wTr  = W1 + (size_t)(kT < 0 ? 0 : 128 + kT) * CP + c0;
    const float* wSr  = W1 + (size_t)(kS < 0 ? 0 : 150 + kS) * CP + c0;
    #pragma unroll
    for (int ch = 0; ch < 4; ++ch) {
        const int cc = ch * 8;
        const float4 qa = *(const float4*)(qrow + cc);
        const float4 qb = *(const float4*)(qrow + cc + 4);
        const float4 ra = *(const float4*)(rrow + cc);
        const float4 rb = *(const float4*)(rrow + cc + 4);
        const float4 ta = *(const float4*)(wTr + cc);
        const float4 tb = *(const float4*)(wTr + cc + 4);
        const float4 sa = *(const float4*)(wSr + cc);
        const float4 sb = *(const float4*)(wSr + cc + 4);
        float h[8];
        h[0] = fmaxf(qa.x + ra.x + fT * ta.x + fS * sa.x, 0.0f);
        h[1] = fmaxf(qa.y + ra.y + fT * ta.y + fS * sa.y, 0.0f);
        h[2] = fmaxf(qa.z + ra.z + fT * ta.z + fS * sa.z, 0.0f);
        h[3] = fmaxf(qa.w + ra.w + fT * ta.w + fS * sa.w, 0.0f);
        h[4] = fmaxf(qb.x + rb.x + fT * tb.x + fS * sb.x, 0.0f);
        h[5] = fmaxf(qb.y + rb.y + fT * tb.y + fS * sb.y, 0.0f);
        h[6] = fmaxf(qb.z + rb.z + fT * tb.z + fS * sb.z, 0.0f);
        h[7] = fmaxf(qb.w + rb.w + fT * tb.w + fS * sb.w, 0.0f);
        bf16x8 H;
        #pragma unroll
        for (int u = 0; u < 8; ++u)
            H[u] = (short)f2bf(h[u]);
        const unsigned int ad = (unsigned int)e1 * 256 +
            (((unsigned int)(2 * (c0 + cc))) ^ (((unsigned int)e1 & 7) << 4));
        *(bf16x8*)(buf + ad) = H;
    }
}

// GEMM layer: acc = bias ; acc += (Wh + Wl) . h_bf16  (h from buf)
__device__ __forceinline__ void gemm_layer(f32x4 acc[2][4],
                                           const char* __restrict__ buf,
                                           const unsigned short* __restrict__ WpH,
                                           const unsigned short* __restrict__ WpL,
                                           const float* __restrict__ bias,
                                           int w, int l, int lr, int lg) {
    #pragma unroll
    for (int mt = 0; mt < 2; ++mt) {
        const float4 bv = *(const float4*)&bias[16 * (2 * w + mt) + 4 * lg];
        #pragma unroll
        for (int nt = 0; nt < 4; ++nt) {
            acc[mt][nt][0] = bv.x; acc[mt][nt][1] = bv.y;
            acc[mt][nt][2] = bv.z; acc[mt][nt][3] = bv.w;
        }
    }
    #pragma unroll
    for (int ki = 0; ki < 4; ++ki) {
        bf16x8 ah[2], al[2];
        #pragma unroll
        for (int mt = 0; mt < 2; ++mt) {
            const size_t off = (((size_t)ki * 8 + (2 * w + mt)) * 64 + l) * 8;
            ah[mt] = *(const bf16x8*)(WpH + off);
            al[mt] = *(const bf16x8*)(WpL + off);
        }
        bf16x8 bh[4];
        #pragma unroll
        for (int nt = 0; nt < 4; ++nt) {
            const int e = 16 * nt + lr;
            const unsigned int ad = (unsigned int)e * 256 +
                (((unsigned int)(64 * ki + 16 * lg)) ^ (((unsigned int)e & 7) << 4));
            bh[nt] = *(const bf16x8*)(buf + ad);
        }
        __builtin_amdgcn_s_setprio(1);
        #pragma unroll
        for (int mt = 0; mt < 2; ++mt)
            #pragma unroll
            for (int nt = 0; nt < 4; ++nt) {
                acc[mt][nt] = __builtin_amdgcn_mfma_f32_16x16x32_bf16(ah[mt], bh[nt], acc[mt][nt], 0, 0, 0);
                acc[mt][nt] = __builtin_amdgcn_mfma_f32_16x16x32_bf16(al[mt], bh[nt], acc[mt][nt], 0, 0, 0);
            }
        __builtin_amdgcn_s_setprio(0);
    }
}

// P3: h2 = relu(acc) -> buf (bf16, transposed [e][n], swizzled)
__device__ __forceinline__ void store_h2(char* __restrict__ buf,
                                         const f32x4 acc[2][4],
                                         int w, int lr, int lg) {
    #pragma unroll
    for (int mt = 0; mt < 2; ++mt) {
        const int mtg = 2 * w + mt;
        #pragma unroll
        for (int nt = 0; nt < 4; ++nt) {
            const int e = 16 * nt + lr;
            bf16x4 H;
            H[0] = (short)f2bf(fmaxf(acc[mt][nt][0], 0.0f));
            H[1] = (short)f2bf(fmaxf(acc[mt][nt][1], 0.0f));
            H[2] = (short)f2bf(fmaxf(acc[mt][nt][2], 0.0f));
            H[3] = (short)f2bf(fmaxf(acc[mt][nt][3], 0.0f));
            const unsigned int ad = (unsigned int)e * 256 +
                (((unsigned int)(32 * mtg + 8 * lg)) ^ (((unsigned int)e & 7) << 4));
            *(bf16x4*)(buf + ad) = H;
        }
    }
}

// LN partials -> scr (psum [64][17] @0, pqsum @4352)
__device__ __forceinline__ void ln_part(char* __restrict__ scr,
                                        const f32x4 acc[2][4],
                                        int w, int lr, int lg) {
    float* psum_s  = (float*)scr;
    float* pqsum_s = (float*)(scr + 4352);
    #pragma unroll
    for (int nt = 0; nt < 4; ++nt) {
        const int e = 16 * nt + lr;
        float s = 0.0f, s2 = 0.0f;
        #pragma unroll
        for (int mt = 0; mt < 2; ++mt)
            #pragma unroll
            for (int r = 0; r < 4; ++r) {
                const float v = acc[mt][nt][r];
                s += v;
                s2 = fmaf(v, v, s2);
            }
        psum_s[e * 17 + 4 * w + lg]  = s;
        pqsum_s[e * 17 + 4 * w + lg] = s2;
    }
}

// LN reduce (redundant per thread): mus @8704, invs @8960
__device__ __forceinline__ void ln_red(char* __restrict__ scr, int t) {
    float* psum_s  = (float*)scr;
    float* pqsum_s = (float*)(scr + 4352);
    float* mus     = (float*)(scr + 8704);
    float* invs    = (float*)(scr + 8960);
    const int e = t & 63;
    float s = 0.0f, s2 = 0.0f;
    #pragma unroll
    for (int k = 0; k < 16; ++k) {
        s  += psum_s[e * 17 + k];
        s2 += pqsum_s[e * 17 + k];
    }
    const float mu  = s * (1.0f / 128.0f);
    const float var = s2 * (1.0f / 128.0f) - mu * mu;
    mus[e]  = mu;
    invs[e] = rsqrtf(var + 1e-5f);
}

// P7: normalize fragments, mask, direct frag store
__device__ __forceinline__ void store_out(float* __restrict__ out,
                                          const float* __restrict__ edge_mask,
                                          const float* __restrict__ ln_g,
                                          const float* __restrict__ ln_b,
                                          const f32x4 acc[2][4],
                                          const char* __restrict__ scr,
                                          int b, int i, int j0,
                                          int w, int lr, int lg) {
    const float* mus  = (const float*)(scr + 8704);
    const float* invs = (const float*)(scr + 8960);
    float4 g4[2], bb4[2];
    #pragma unroll
    for (int mt = 0; mt < 2; ++mt) {
        const int n0 = 16 * (2 * w + mt) + 4 * lg;
        g4[mt]  = *(const float4*)&ln_g[n0];
        bb4[mt] = *(const float4*)&ln_b[n0];
    }
    #pragma unroll
    for (int nt = 0; nt < 4; ++nt) {
        const int e = 16 * nt + lr;
        const size_t erow = ((size_t)(b * NN + i)) * NN + (j0 + e);
        const float em  = edge_mask[erow];
        const float mu  = mus[e];
        const float inv = invs[e];
        float* op = out + erow * CP;
        #pragma unroll
        for (int mt = 0; mt < 2; ++mt) {
            const int n0 = 16 * (2 * w + mt) + 4 * lg;
            float4 o;
            o.x = ((acc[mt][nt][0] - mu) * inv * g4[mt].x + bb4[mt].x) * em;
            o.y = ((acc[mt][nt][1] - mu) * inv * g4[mt].y + bb4[mt].y) * em;
            o.z = ((acc[mt][nt][2] - mu) * inv * g4[mt].z + bb4[mt].z) * em;
            o.w = ((acc[mt][nt][3] - mu) * inv * g4[mt].w + bb4[mt].w) * em;
            *(float4*)(op + n0) = o;
        }
    }
}

// ---------------------------------------------------------------------------
// Prep kernel: blocks [0,1024) = per-node q/r precompute; [1024,1088) = W pack.
// ---------------------------------------------------------------------------
__global__ __launch_bounds__(256) void ef_prep_kernel(
    const float* __restrict__ x,
    const float* __restrict__ diffuse,
    const float* __restrict__ Wsp,
    const float* __restrict__ bsp,
    const float* __restrict__ W1,
    const float* __restrict__ b1,
    const float* __restrict__ W2,
    const float* __restrict__ W3,
    float* __restrict__ qr,
    unsigned short* __restrict__ Wp)
{
    __shared__ float xs[CS];
    __shared__ float ps[FD];
    const int t = threadIdx.x;
    if (blockIdx.x < 1024) {
        const int n = blockIdx.x;
        xs[t] = x[(size_t)n * CS + t];
        __syncthreads();
        if (t < FD) {
            float acc = bsp[t];
            #pragma unroll 8
            for (int k = 0; k < CS; ++k)
                acc = fmaf(xs[k], Wsp[k * FD + t], acc);
            ps[t] = acc;
        }
        __syncthreads();
        const float dm = diffuse[n];
        const int c = t & (CP - 1);
        if (t < CP) {
            float acc = b1[c] + dm * W1[172 * CP + c];
            #pragma unroll 8
            for (int k = 0; k < FD; ++k)
                acc = fmaf(ps[k], W1[k * CP + c], acc);
            qr[(size_t)n * CP + c] = acc;
        } else {
            float acc = dm * W1[173 * CP + c];
            #pragma unroll 8
            for (int k = 0; k < FD; ++k)
                acc = fmaf(ps[k], W1[(FD + k) * CP + c], acc);
            qr[(size_t)(1024 + n) * CP + c] = acc;
        }
    } else {
        const int s = (blockIdx.x - 1024) * 256 + t;   // 0..16383
        const int j    = s & 7;
        const int lane = (s >> 3) & 63;
        const int mt   = (s >> 9) & 7;
        const int ki   = s >> 12;
        const int k = 32 * ki + 8 * (lane >> 4) + j;
        const int n = 16 * mt + (lane & 15);
        const float w2 = W2[k * CP + n];
        const float w3 = W3[k * CP + n];
        const unsigned short h2 = f2bf_rne(w2);
        const unsigned short l2 = f2bf_rne(w2 - bf2f(h2));
        const unsigned short h3 = f2bf_rne(w3);
        const unsigned short l3 = f2bf_rne(w3 - bf2f(h3));
        Wp[s]         = h2;
        Wp[16384 + s] = l2;
        Wp[32768 + s] = h3;
        Wp[49152 + s] = l3;
    }
}

// ---------------------------------------------------------------------------
// Edge kernel: TWO 64-edge tiles per block (A,B), software-pipelined phases.
// Every barrier covers independent work from both tiles (ILP fills the L2
// load chains that 4-wave TLP could not hide). 7 barriers per 2 tiles.
// LDS: bufA 16K | bufB 16K; LN scratch carved inside each buf once h2 dead.
// ---------------------------------------------------------------------------
__global__ __launch_bounds__(256, 4) void ef_edge_kernel(
    const float* __restrict__ trans_t,
    const float* __restrict__ trans_sc,
    const float* __restrict__ edge_mask,
    const float* __restrict__ W1,
    const float* __restrict__ b2,
    const float* __restrict__ b3,
    const float* __restrict__ ln_g,
    const float* __restrict__ ln_b,
    const float* __restrict__ qr,
    const unsigned short* __restrict__ Wp,
    float* __restrict__ out)
{
    __shared__ char hb8[32768];
    char* bufA = hb8;
    char* bufB = hb8 + 16384;

    const int t   = threadIdx.x;
    const int blk = blockIdx.x;
    const int jtp = blk & 3;
    const int i   = (blk >> 2) & (NN - 1);
    const int b   = blk >> 11;
    const int j0A = jtp * 128;
    const int j0B = j0A + 64;
    const int nodeI = b * NN + i;

    const int w  = t >> 6;
    const int l  = t & 63;
    const int lr = l & 15;
    const int lg = l >> 4;
    const int e1 = t >> 2;
    const int c0 = (t & 3) * 32;
    const int njA = b * NN + j0A + e1;
    const int njB = b * NN + j0B + e1;

    const float step = __fdiv_rn(__fsub_rn(20.0f, 0.001f), 21.0f);

    // ---- S0: bins(A) + h1(A) -> bufA ----
    int kTA, kSA;
    calc_bins(trans_t, trans_sc, nodeI, njA, step, kTA, kSA);
    build_h1(bufA, qr, W1, nodeI, njA, kTA, kSA, e1, c0);
    __syncthreads();                                   // bar1: h1(A) ready

    // ---- S1: bins(B) | L2-GEMM(A) | h1(B) -> bufB ----
    int kTB, kSB;
    calc_bins(trans_t, trans_sc, nodeI, njB, step, kTB, kSB);
    f32x4 accA[2][4];
    gemm_layer(accA, bufA, Wp, Wp + 16384, b2, w, l, lr, lg);
    build_h1(bufB, qr, W1, nodeI, njB, kTB, kSB, e1, c0);
    __syncthreads();                                   // bar2: h1(A) reads done; h1(B) ready

    // ---- S2: h2(A) -> bufA | L2-GEMM(B) ----
    store_h2(bufA, accA, w, lr, lg);
    f32x4 accB[2][4];
    gemm_layer(accB, bufB, Wp, Wp + 16384, b2, w, l, lr, lg);
    __syncthreads();                                   // bar3: h2(A) ready; h1(B) reads done

    // ---- S3: h2(B) -> bufB | L3-GEMM(A) ----
    store_h2(bufB, accB, w, lr, lg);
    gemm_layer(accA, bufA, Wp + 32768, Wp + 49152, b3, w, l, lr, lg);
    __syncthreads();                                   // bar4: h2(A) reads done; h2(B) ready

    // ---- S4: LN-partials(A) -> scrA (in bufA) | L3-GEMM(B) ----
    ln_part(bufA, accA, w, lr, lg);
    gemm_layer(accB, bufB, Wp + 32768, Wp + 49152, b3, w, l, lr, lg);
    __syncthreads();                                   // bar5: scrA ready; h2(B) reads done

    // ---- S5: LN-reduce(A) | LN-partials(B) -> scrB (in bufB) ----
    ln_red(bufA, t);
    ln_part(bufB, accB, w, lr, lg);
    __syncthreads();                                   // bar6: mus/invs(A) ready; scrB ready

    // ---- S6: store(A) | LN-reduce(B) ----
    store_out(out, edge_mask, ln_g, ln_b, accA, bufA, b, i, j0A, w, lr, lg);
    ln_red(bufB, t);
    __syncthreads();                                   // bar7: mus/invs(B) ready

    // ---- S7: store(B) ----
    store_out(out, edge_mask, ln_g, ln_b, accB, bufB, b, i, j0B, w, lr, lg);
}

extern "C" void kernel_launch(void* const* d_in, const int* in_sizes, int n_in,
                              void* d_out, int out_size, void* d_ws, size_t ws_size,
                              hipStream_t stream) {
    const float* init_node = (const float*)d_in[0];
    const float* trans_t   = (const float*)d_in[1];
    const float* trans_sc  = (const float*)d_in[2];
    const float* edge_mask = (const float*)d_in[3];
    const float* diffuse   = (const float*)d_in[4];
    const float* Wsp       = (const float*)d_in[5];
    const float* bsp       = (const float*)d_in[6];
    const float* W1        = (const float*)d_in[7];
    const float* b1        = (const float*)d_in[8];
    const float* W2        = (const float*)d_in[9];
    const float* b2        = (const float*)d_in[10];
    const float* W3        = (const float*)d_in[11];
    const float* b3        = (const float*)d_in[12];
    const float* ln_g      = (const float*)d_in[13];
    const float* ln_b      = (const float*)d_in[14];
    float* out = (float*)d_out;
    float* qr  = (float*)d_ws;                                       // 1 MiB
    unsigned short* Wp = (unsigned short*)((char*)d_ws + (1 << 20)); // 128 KiB

    ef_prep_kernel<<<1024 + 64, 256, 0, stream>>>(
        init_node, diffuse, Wsp, bsp, W1, b1, W2, W3, qr, Wp);
    ef_edge_kernel<<<NB * NN * (NN / EPB / 2), 256, 0, stream>>>(
        trans_t, trans_sc, edge_mask, W1, b2, b3, ln_g, ln_b, qr, Wp, out);
}

// Round 17
// 205.155 us; speedup vs baseline: 1.4060x; 1.4060x over previous
//
#include <hip/hip_runtime.h>
#include <hip/hip_bf16.h>
#include <math.h>

#define NB 2
#define NN 512
#define CS 256
#define CP 128
#define FD 64
#define NBINS 22
#define EPB 64

typedef __attribute__((ext_vector_type(8))) short bf16x8;
typedef __attribute__((ext_vector_type(4))) short bf16x4;
typedef __attribute__((ext_vector_type(4))) float f32x4;

__device__ __forceinline__ unsigned short f2bf_rne(float x) {
    unsigned int u = __float_as_uint(x);
    unsigned int r = (u + 0x7fffu + ((u >> 16) & 1u)) >> 16;
    return (unsigned short)r;
}
__device__ __forceinline__ float bf2f(unsigned short b) {
    return __uint_as_float(((unsigned int)b) << 16);
}
__device__ __forceinline__ unsigned short f2bf(float x) {
    __hip_bfloat16 h = __float2bfloat16(x);
    unsigned short u;
    __builtin_memcpy(&u, &h, 2);
    return u;
}

// Guarded-floor bin: exact fp32 boundary semantics of the reference scan.
__device__ __forceinline__ int bin_of(float d, float step) {
    const float fk = __fdiv_rn(__fsub_rn(d, 0.001f), step);
    int k0 = (int)fk;
    k0 = k0 < 1 ? 1 : (k0 > 20 ? 20 : k0);
    int row = -1;
    #pragma unroll
    for (int dk = -1; dk <= 1; ++dk) {
        const int k = k0 + dk;
        const float lo = __fadd_rn(0.001f, __fmul_rn((float)k, step));
        const float hi = (k == NBINS - 1)
                       ? 1e8f
                       : __fadd_rn(0.001f, __fmul_rn((float)(k + 1), step));
        row = (d > lo && d < hi) ? k : row;
    }
    return row;
}

// ---------------------------------------------------------------------------
// Prep kernel: blocks [0,1024) = per-node q/r precompute; [1024,1088) = W pack.
// Wp: [4][16384] ushort {W2h, W2l, W3h, W3l}, per-lane MFMA A-frag order.
// ---------------------------------------------------------------------------
__global__ __launch_bounds__(256) void ef_prep_kernel(
    const float* __restrict__ x,
    const float* __restrict__ diffuse,
    const float* __restrict__ Wsp,
    const float* __restrict__ bsp,
    const float* __restrict__ W1,
    const float* __restrict__ b1,
    const float* __restrict__ W2,
    const float* __restrict__ W3,
    float* __restrict__ qr,
    unsigned short* __restrict__ Wp)
{
    __shared__ float xs[CS];
    __shared__ float ps[FD];
    const int t = threadIdx.x;
    if (blockIdx.x < 1024) {
        const int n = blockIdx.x;
        xs[t] = x[(size_t)n * CS + t];
        __syncthreads();
        if (t < FD) {
            float acc = bsp[t];
            #pragma unroll 8
            for (int k = 0; k < CS; ++k)
                acc = fmaf(xs[k], Wsp[k * FD + t], acc);
            ps[t] = acc;
        }
        __syncthreads();
        const float dm = diffuse[n];
        const int c = t & (CP - 1);
        if (t < CP) {
            float acc = b1[c] + dm * W1[172 * CP + c];
            #pragma unroll 8
            for (int k = 0; k < FD; ++k)
                acc = fmaf(ps[k], W1[k * CP + c], acc);
            qr[(size_t)n * CP + c] = acc;
        } else {
            float acc = dm * W1[173 * CP + c];
            #pragma unroll 8
            for (int k = 0; k < FD; ++k)
                acc = fmaf(ps[k], W1[(FD + k) * CP + c], acc);
            qr[(size_t)(1024 + n) * CP + c] = acc;
        }
    } else {
        const int s = (blockIdx.x - 1024) * 256 + t;   // 0..16383
        const int j    = s & 7;
        const int lane = (s >> 3) & 63;
        const int mt   = (s >> 9) & 7;
        const int ki   = s >> 12;
        const int k = 32 * ki + 8 * (lane >> 4) + j;
        const int n = 16 * mt + (lane & 15);
        const float w2 = W2[k * CP + n];
        const float w3 = W3[k * CP + n];
        const unsigned short h2 = f2bf_rne(w2);
        const unsigned short l2 = f2bf_rne(w2 - bf2f(h2));
        const unsigned short h3 = f2bf_rne(w3);
        const unsigned short l3 = f2bf_rne(w3 - bf2f(h3));
        Wp[s]         = h2;
        Wp[16384 + s] = l2;
        Wp[32768 + s] = h3;
        Wp[49152 + s] = l3;
    }
}

// ---------------------------------------------------------------------------
// Edge kernel: r12 champion (202 us, passed 3x) + ONE provably-safe delta:
// dual LDS planes. h1 -> plane A [0,16K), h2 -> plane B [16K,32K), LN
// scratch in plane A (dead after P2; bar2 proves all P2 reads done since P3
// follows P2 in program order). Deletes champion barriers 2 and 4:
//   P1 -> bar1 -> P2(read A) | P3(write B) -> bar2 -> P4(read B) |
//   P5(write A-scratch) -> bar3 -> P6 -> bar4 -> P7.
// Everything else (GEMM shapes, swizzles, LN arrays, stores) is byte-identical
// to the champion. The shfl-LN restructure (r9/r10/r16 failures) is NOT used.
// ---------------------------------------------------------------------------
__global__ __launch_bounds__(256, 4) void ef_edge_kernel(
    const float* __restrict__ trans_t,
    const float* __restrict__ trans_sc,
    const float* __restrict__ edge_mask,
    const float* __restrict__ W1,
    const float* __restrict__ b2,
    const float* __restrict__ b3,
    const float* __restrict__ ln_g,
    const float* __restrict__ ln_b,
    const float* __restrict__ qr,
    const unsigned short* __restrict__ Wp,
    float* __restrict__ out)
{
    __shared__ char hb8[32768];
    char* h1buf = hb8;            // plane A: h1 (bf16, swizzled); later LN scratch
    char* h2buf = hb8 + 16384;    // plane B: h2 (bf16, swizzled)
    float* psum_s  = (float*)hb8;            // [64][17]  (4352 B)  in plane A
    float* pqsum_s = (float*)(hb8 + 4352);   // [64][17]  (4352 B)
    float* mus     = (float*)(hb8 + 8704);   // [64]
    float* invs    = (float*)(hb8 + 8960);   // [64]      (ends 9216 <= 16384)

    const int t   = threadIdx.x;
    const int blk = blockIdx.x;
    const int jt  = blk & 7;
    const int i   = (blk >> 3) & (NN - 1);
    const int b   = blk >> 12;
    const int j0  = jt * EPB;
    const int nodeI  = b * NN + i;
    const int nodeJ0 = b * NN + j0;

    const int w  = t >> 6;
    const int l  = t & 63;
    const int lr = l & 15;
    const int lg = l >> 4;
    const int e1 = t >> 2;
    const int c0 = (t & 3) * 32;
    const int nj = nodeJ0 + e1;

    // ---- bins (per-thread, 4x redundant, no LDS, no barrier) ----
    const float step = __fdiv_rn(__fsub_rn(20.0f, 0.001f), 21.0f);
    float dx = __fsub_rn(trans_t[nodeI * 3 + 0], trans_t[nj * 3 + 0]);
    float dy = __fsub_rn(trans_t[nodeI * 3 + 1], trans_t[nj * 3 + 1]);
    float dz = __fsub_rn(trans_t[nodeI * 3 + 2], trans_t[nj * 3 + 2]);
    const float dT = sqrtf(__fadd_rn(__fadd_rn(__fmul_rn(dx, dx), __fmul_rn(dy, dy)), __fmul_rn(dz, dz)));
    dx = __fsub_rn(trans_sc[nodeI * 3 + 0], trans_sc[nj * 3 + 0]);
    dy = __fsub_rn(trans_sc[nodeI * 3 + 1], trans_sc[nj * 3 + 1]);
    dz = __fsub_rn(trans_sc[nodeI * 3 + 2], trans_sc[nj * 3 + 2]);
    const float dS = sqrtf(__fadd_rn(__fadd_rn(__fmul_rn(dx, dx), __fmul_rn(dy, dy)), __fmul_rn(dz, dz)));
    const int kT = bin_of(dT, step);
    const int kS = bin_of(dS, step);

    // ---- P1: h1 = relu(q_i + r_j + W1[binT] + W1[binS]) -> plane A ----
    {
        const float fT = (kT < 0) ? 0.0f : 1.0f;
        const float fS = (kS < 0) ? 0.0f : 1.0f;
        const float* qrow = qr + (size_t)nodeI * CP + c0;
        const float* rrow = qr + (size_t)(1024 + nj) * CP + c0;
        const float* wTr  = W1 + (size_t)(kT < 0 ? 0 : 128 + kT) * CP + c0;
        const float* wSr  = W1 + (size_t)(kS < 0 ? 0 : 150 + kS) * CP + c0;
        #pragma unroll
        for (int ch = 0; ch < 4; ++ch) {
            const int cc = ch * 8;
            const float4 qa = *(const float4*)(qrow + cc);
            const float4 qb = *(const float4*)(qrow + cc + 4);
            const float4 ra = *(const float4*)(rrow + cc);
            const float4 rb = *(const float4*)(rrow + cc + 4);
            const float4 ta = *(const float4*)(wTr + cc);
            const float4 tb = *(const float4*)(wTr + cc + 4);
            const float4 sa = *(const float4*)(wSr + cc);
            const float4 sb = *(const float4*)(wSr + cc + 4);
            float h[8];
            h[0] = fmaxf(qa.x + ra.x + fT * ta.x + fS * sa.x, 0.0f);
            h[1] = fmaxf(qa.y + ra.y + fT * ta.y + fS * sa.y, 0.0f);
            h[2] = fmaxf(qa.z + ra.z + fT * ta.z + fS * sa.z, 0.0f);
            h[3] = fmaxf(qa.w + ra.w + fT * ta.w + fS * sa.w, 0.0f);
            h[4] = fmaxf(qb.x + rb.x + fT * tb.x + fS * sb.x, 0.0f);
            h[5] = fmaxf(qb.y + rb.y + fT * tb.y + fS * sb.y, 0.0f);
            h[6] = fmaxf(qb.z + rb.z + fT * tb.z + fS * sb.z, 0.0f);
            h[7] = fmaxf(qb.w + rb.w + fT * tb.w + fS * sb.w, 0.0f);
            bf16x8 H;
            #pragma unroll
            for (int u = 0; u < 8; ++u)
                H[u] = (short)f2bf(h[u]);
            const unsigned int ad = (unsigned int)e1 * 256 +
                (((unsigned int)(2 * (c0 + cc))) ^ (((unsigned int)e1 & 7) << 4));
            *(bf16x8*)(h1buf + ad) = H;
        }
    }
    __syncthreads();   // barrier 1: h1 ready

    // ---- P2: layer-2 MFMA: C = (W2h + W2l) . h1 (reads plane A) ----
    f32x4 acc[2][4];
    #pragma unroll
    for (int mt = 0; mt < 2; ++mt) {
        const float4 bv = *(const float4*)&b2[16 * (2 * w + mt) + 4 * lg];
        #pragma unroll
        for (int nt = 0; nt < 4; ++nt) {
            acc[mt][nt][0] = bv.x; acc[mt][nt][1] = bv.y;
            acc[mt][nt][2] = bv.z; acc[mt][nt][3] = bv.w;
        }
    }
    #pragma unroll
    for (int ki = 0; ki < 4; ++ki) {
        bf16x8 ah[2], al[2];
        #pragma unroll
        for (int mt = 0; mt < 2; ++mt) {
            const size_t off = (((size_t)ki * 8 + (2 * w + mt)) * 64 + l) * 8;
            ah[mt] = *(const bf16x8*)(Wp + off);
            al[mt] = *(const bf16x8*)(Wp + 16384 + off);
        }
        bf16x8 bh[4];
        #pragma unroll
        for (int nt = 0; nt < 4; ++nt) {
            const int e = 16 * nt + lr;
            const unsigned int ad = (unsigned int)e * 256 +
                (((unsigned int)(64 * ki + 16 * lg)) ^ (((unsigned int)e & 7) << 4));
            bh[nt] = *(const bf16x8*)(h1buf + ad);
        }
        __builtin_amdgcn_s_setprio(1);
        #pragma unroll
        for (int mt = 0; mt < 2; ++mt)
            #pragma unroll
            for (int nt = 0; nt < 4; ++nt) {
                acc[mt][nt] = __builtin_amdgcn_mfma_f32_16x16x32_bf16(ah[mt], bh[nt], acc[mt][nt], 0, 0, 0);
                acc[mt][nt] = __builtin_amdgcn_mfma_f32_16x16x32_bf16(al[mt], bh[nt], acc[mt][nt], 0, 0, 0);
            }
        __builtin_amdgcn_s_setprio(0);
    }

    // ---- P3: h2 = relu(acc) -> plane B (disjoint from A: no barrier) ----
    #pragma unroll
    for (int mt = 0; mt < 2; ++mt) {
        const int mtg = 2 * w + mt;
        #pragma unroll
        for (int nt = 0; nt < 4; ++nt) {
            const int e = 16 * nt + lr;
            bf16x4 H;
            H[0] = (short)f2bf(fmaxf(acc[mt][nt][0], 0.0f));
            H[1] = (short)f2bf(fmaxf(acc[mt][nt][1], 0.0f));
            H[2] = (short)f2bf(fmaxf(acc[mt][nt][2], 0.0f));
            H[3] = (short)f2bf(fmaxf(acc[mt][nt][3], 0.0f));
            const unsigned int ad = (unsigned int)e * 256 +
                (((unsigned int)(32 * mtg + 8 * lg)) ^ (((unsigned int)e & 7) << 4));
            *(bf16x4*)(h2buf + ad) = H;
        }
    }
    __syncthreads();   // barrier 2: h2 ready; also proves all P2 reads of A done

    // ---- P4: layer-3 MFMA into the SAME acc (re-init with b3, reads plane B) ----
    #pragma unroll
    for (int mt = 0; mt < 2; ++mt) {
        const float4 bv = *(const float4*)&b3[16 * (2 * w + mt) + 4 * lg];
        #pragma unroll
        for (int nt = 0; nt < 4; ++nt) {
            acc[mt][nt][0] = bv.x; acc[mt][nt][1] = bv.y;
            acc[mt][nt][2] = bv.z; acc[mt][nt][3] = bv.w;
        }
    }
    #pragma unroll
    for (int ki = 0; ki < 4; ++ki) {
        bf16x8 ah[2], al[2];
        #pragma unroll
        for (int mt = 0; mt < 2; ++mt) {
            const size_t off = (((size_t)ki * 8 + (2 * w + mt)) * 64 + l) * 8;
            ah[mt] = *(const bf16x8*)(Wp + 32768 + off);
            al[mt] = *(const bf16x8*)(Wp + 49152 + off);
        }
        bf16x8 bh[4];
        #pragma unroll
        for (int nt = 0; nt < 4; ++nt) {
            const int e = 16 * nt + lr;
            const unsigned int ad = (unsigned int)e * 256 +
                (((unsigned int)(64 * ki + 16 * lg)) ^ (((unsigned int)e & 7) << 4));
            bh[nt] = *(const bf16x8*)(h2buf + ad);
        }
        __builtin_amdgcn_s_setprio(1);
        #pragma unroll
        for (int mt = 0; mt < 2; ++mt)
            #pragma unroll
            for (int nt = 0; nt < 4; ++nt) {
                acc[mt][nt] = __builtin_amdgcn_mfma_f32_16x16x32_bf16(ah[mt], bh[nt], acc[mt][nt], 0, 0, 0);
                acc[mt][nt] = __builtin_amdgcn_mfma_f32_16x16x32_bf16(al[mt], bh[nt], acc[mt][nt], 0, 0, 0);
            }
        __builtin_amdgcn_s_setprio(0);
    }

    // ---- P5: LN partial sums -> plane-A scratch (A dead since barrier 2;
    //          disjoint from P4's plane-B reads: no barrier) ----
    #pragma unroll
    for (int nt = 0; nt < 4; ++nt) {
        const int e = 16 * nt + lr;
        float s = 0.0f, s2 = 0.0f;
        #pragma unroll
        for (int mt = 0; mt < 2; ++mt)
            #pragma unroll
            for (int r = 0; r < 4; ++r) {
                const float v = acc[mt][nt][r];
                s += v;
                s2 = fmaf(v, v, s2);
            }
        psum_s[e * 17 + 4 * w + lg]  = s;
        pqsum_s[e * 17 + 4 * w + lg] = s2;
    }
    __syncthreads();   // barrier 3: LN partials ready

    // ---- P6: LN reduce (redundant per thread, e = t & 63) ----
    {
        const int e = t & 63;
        float s = 0.0f, s2 = 0.0f;
        #pragma unroll
        for (int k = 0; k < 16; ++k) {
            s  += psum_s[e * 17 + k];
            s2 += pqsum_s[e * 17 + k];
        }
        const float mu  = s * (1.0f / 128.0f);
        const float var = s2 * (1.0f / 128.0f) - mu * mu;
        mus[e]  = mu;
        invs[e] = rsqrtf(var + 1e-5f);
    }
    __syncthreads();   // barrier 4: mus/invs ready

    // ---- P7: normalize fragments in-register, mask, direct frag store ----
    {
        float4 g4[2], bb4[2];
        #pragma unroll
        for (int mt = 0; mt < 2; ++mt) {
            const int n0 = 16 * (2 * w + mt) + 4 * lg;
            g4[mt]  = *(const float4*)&ln_g[n0];
            bb4[mt] = *(const float4*)&ln_b[n0];
        }
        #pragma unroll
        for (int nt = 0; nt < 4; ++nt) {
            const int e = 16 * nt + lr;
            const size_t erow = ((size_t)(b * NN + i)) * NN + (j0 + e);
            const float em  = edge_mask[erow];
            const float mu  = mus[e];
            const float inv = invs[e];
            float* op = out + erow * CP;
            #pragma unroll
            for (int mt = 0; mt < 2; ++mt) {
                const int n0 = 16 * (2 * w + mt) + 4 * lg;
                float4 o;
                o.x = ((acc[mt][nt][0] - mu) * inv * g4[mt].x + bb4[mt].x) * em;
                o.y = ((acc[mt][nt][1] - mu) * inv * g4[mt].y + bb4[mt].y) * em;
                o.z = ((acc[mt][nt][2] - mu) * inv * g4[mt].z + bb4[mt].z) * em;
                o.w = ((acc[mt][nt][3] - mu) * inv * g4[mt].w + bb4[mt].w) * em;
                *(float4*)(op + n0) = o;
            }
        }
    }
}

extern "C" void kernel_launch(void* const* d_in, const int* in_sizes, int n_in,
                              void* d_out, int out_size, void* d_ws, size_t ws_size,
                              hipStream_t stream) {
    const float* init_node = (const float*)d_in[0];
    const float* trans_t   = (const float*)d_in[1];
    const float* trans_sc  = (const float*)d_in[2];
    const float* edge_mask = (const float*)d_in[3];
    const float* diffuse   = (const float*)d_in[4];
    const float* Wsp       = (const float*)d_in[5];
    const float* bsp       = (const float*)d_in[6];
    const float* W1        = (const float*)d_in[7];
    const float* b1        = (const float*)d_in[8];
    const float* W2        = (const float*)d_in[9];
    const float* b2        = (const float*)d_in[10];
    const float* W3        = (const float*)d_in[11];
    const float* b3        = (const float*)d_in[12];
    const float* ln_g      = (const float*)d_in[13];
    const float* ln_b      = (const float*)d_in[14];
    float* out = (float*)d_out;
    float* qr  = (float*)d_ws;                                       // 1 MiB
    unsigned short* Wp = (unsigned short*)((char*)d_ws + (1 << 20)); // 128 KiB

    ef_prep_kernel<<<1024 + 64, 256, 0, stream>>>(
        init_node, diffuse, Wsp, bsp, W1, b1, W2, W3, qr, Wp);
    ef_edge_kernel<<<NB * NN * (NN / EPB), 256, 0, stream>>>(
        trans_t, trans_sc, edge_mask, W1, b2, b3, ln_g, ln_b, qr, Wp, out);
}